// Round 5
// baseline (18.967 us; speedup 1.0000x reference)
//
#include <hip/hip_runtime.h>
#include <float.h>

// SpanMaxPooler: out[b, i*H + h] = valid(b,i) ? max_{s in [start,end)} hidden[b,s,h]
//                                            : missing[i,h]
// B=64, S=512, H=1024, I=2. Spans are 1..32 rows. Latency-bound tiny kernel.
//
// R5: R4's one-burst structure, power-of-two variants ONLY (8/16/32 loads).
// R4's bug: the pairwise tree reduction is only correct for power-of-two R
// (R=24 dropped v[2] at the stride-3 -> stride-1 step). Tail rows clamp to
// n-1 — max is idempotent, dupes are L1 hits.

#define FMAX4(a, v)            \
    (a).x = fmaxf((a).x, (v).x);   \
    (a).y = fmaxf((a).y, (v).y);   \
    (a).z = fmaxf((a).z, (v).z);   \
    (a).w = fmaxf((a).w, (v).w);

template <int R, int H>
__device__ inline float4 reduce_rows(const float* __restrict__ base, int n) {
    static_assert((R & (R - 1)) == 0, "tree reduction requires power-of-two R");
    float4 v[R];
    // all R loads issue before any use -> one load-latency total
    #pragma unroll
    for (int k = 0; k < R; ++k) {
        v[k] = *reinterpret_cast<const float4*>(base + (size_t)min(k, n - 1) * H);
    }
    // pairwise tree reduction (depth log2(R))
    #pragma unroll
    for (int stride = R / 2; stride >= 1; stride >>= 1) {
        #pragma unroll
        for (int k = 0; k < stride; ++k) {
            FMAX4(v[k], v[k + stride]);
        }
    }
    return v[0];
}

template <int S, int H, int I, int SPLIT>
__global__ __launch_bounds__(H / SPLIT / 4) void span_max_kernel(
    const float* __restrict__ hidden,   // [B,S,H]
    const int*   __restrict__ start,    // [B,I]
    const int*   __restrict__ end,      // [B,I]
    const float* __restrict__ missing,  // [I,H]
    float*       __restrict__ out)      // [B,I*H]
{
    const int blk  = blockIdx.x;
    const int part = blk % SPLIT;
    const int span = blk / SPLIT;            // b*I + i
    const int b    = span / I;
    const int i    = span % I;
    const int h0   = part * (H / SPLIT) + threadIdx.x * 4;

    const int s0 = start[span];              // block-uniform
    const int s1 = end[span];

    float4 acc;
    if (s0 < 0 || s1 < 0) {                  // block-uniform branch
        acc = *reinterpret_cast<const float4*>(&missing[(size_t)i * H + h0]);
    } else {
        const int n = s1 - s0;               // 1..32
        const float* base = hidden + (size_t)b * S * H + (size_t)s0 * H + h0;
        if (n <= 8) {
            acc = reduce_rows<8, H>(base, n);
        } else if (n <= 16) {
            acc = reduce_rows<16, H>(base, n);
        } else {
            acc = reduce_rows<32, H>(base, n);
        }
    }

    *reinterpret_cast<float4*>(&out[(size_t)span * H + h0]) = acc;
}

extern "C" void kernel_launch(void* const* d_in, const int* in_sizes, int n_in,
                              void* d_out, int out_size, void* d_ws, size_t ws_size,
                              hipStream_t stream) {
    constexpr int B = 64, S = 512, H = 1024, I = 2;
    constexpr int SPLIT = 2;   // 2 blocks per (b,i) -> 256 blocks (1/CU)

    const float* hidden  = (const float*)d_in[0];
    const int*   start   = (const int*)d_in[1];
    const int*   end     = (const int*)d_in[2];
    const float* missing = (const float*)d_in[3];
    float*       out     = (float*)d_out;

    const int grid  = B * I * SPLIT;       // 256
    const int block = H / SPLIT / 4;       // 128 threads, float4 each

    span_max_kernel<S, H, I, SPLIT><<<grid, block, 0, stream>>>(
        hidden, start, end, missing, out);
}

// Round 6
// 9.377 us; speedup vs baseline: 2.0227x; 2.0227x over previous
//
#include <hip/hip_runtime.h>
#include <float.h>

// SpanMaxPooler: out[b, i*H + h] = valid(b,i) ? max_{s in [start,end)} hidden[b,s,h]
//                                            : missing[i,h]
// B=64, S=512, H=1024, I=2. Spans are 1..32 rows. Latency-bound tiny kernel.
//
// R6 = exact revert to R3 (best measured: 9.4 us, at the ~10 us launch floor).
// Structure: 128-thread blocks, SPLIT=2 (256 blocks), no LDS, no barriers.
// Span walk in paced batches of 8 independent CLAMPED loads (min(s+k, n-1));
// max is idempotent so clamp dupes are harmless L1 hits.
//
// Failed alternatives (measured): R2 row-parallel waves + LDS barrier = 17.6us;
// R5 single 32-deep load burst (vmcnt(0) full-drain wait, ~130 live VGPRs)
// = 19.0us. Paced batches beat both.

#define FMAX4(a, v)            \
    a.x = fmaxf(a.x, (v).x);   \
    a.y = fmaxf(a.y, (v).y);   \
    a.z = fmaxf(a.z, (v).z);   \
    a.w = fmaxf(a.w, (v).w);

template <int S, int H, int I, int SPLIT>
__global__ __launch_bounds__(H / SPLIT / 4) void span_max_kernel(
    const float* __restrict__ hidden,   // [B,S,H]
    const int*   __restrict__ start,    // [B,I]
    const int*   __restrict__ end,      // [B,I]
    const float* __restrict__ missing,  // [I,H]
    float*       __restrict__ out)      // [B,I*H]
{
    constexpr int BATCH = 8;                 // independent loads in flight
    const int blk  = blockIdx.x;
    const int part = blk % SPLIT;
    const int span = blk / SPLIT;            // b*I + i
    const int b    = span / I;
    const int i    = span % I;
    const int h0   = part * (H / SPLIT) + threadIdx.x * 4;

    const int s0 = start[span];              // block-uniform
    const int s1 = end[span];

    float4 acc;
    if (s0 < 0 || s1 < 0) {                  // block-uniform branch
        acc = *reinterpret_cast<const float4*>(&missing[(size_t)i * H + h0]);
    } else {
        const int n = s1 - s0;               // 1..32
        const float* base = hidden + (size_t)b * S * H + (size_t)s0 * H + h0;

        // batch 0: rows 0..7 clamped to n-1 (dupes hit L1; max is idempotent)
        float4 v[BATCH];
        #pragma unroll
        for (int k = 0; k < BATCH; ++k) {
            v[k] = *reinterpret_cast<const float4*>(base + (size_t)min(k, n - 1) * H);
        }
        acc = v[0];
        #pragma unroll
        for (int k = 1; k < BATCH; ++k) { FMAX4(acc, v[k]); }

        // remaining batches (at most 3 iterations for n <= 32)
        for (int s = BATCH; s < n; s += BATCH) {
            #pragma unroll
            for (int k = 0; k < BATCH; ++k) {
                v[k] = *reinterpret_cast<const float4*>(base + (size_t)min(s + k, n - 1) * H);
            }
            #pragma unroll
            for (int k = 0; k < BATCH; ++k) { FMAX4(acc, v[k]); }
        }
    }

    *reinterpret_cast<float4*>(&out[(size_t)span * H + h0]) = acc;
}

extern "C" void kernel_launch(void* const* d_in, const int* in_sizes, int n_in,
                              void* d_out, int out_size, void* d_ws, size_t ws_size,
                              hipStream_t stream) {
    constexpr int B = 64, S = 512, H = 1024, I = 2;
    constexpr int SPLIT = 2;   // 2 blocks per (b,i) -> 256 blocks (1/CU)

    const float* hidden  = (const float*)d_in[0];
    const int*   start   = (const int*)d_in[1];
    const int*   end     = (const int*)d_in[2];
    const float* missing = (const float*)d_in[3];
    float*       out     = (float*)d_out;

    const int grid  = B * I * SPLIT;       // 256
    const int block = H / SPLIT / 4;       // 128 threads, float4 each

    span_max_kernel<S, H, I, SPLIT><<<grid, block, 0, stream>>>(
        hidden, start, end, missing, out);
}